// Round 1
// 578.758 us; speedup vs baseline: 1.0866x; 1.0866x over previous
//
#include <hip/hip_runtime.h>
#include <hip/hip_bf16.h>
#include <stdint.h>

typedef __bf16 bf16_t;
typedef __bf16 bf16x8 __attribute__((ext_vector_type(8)));
typedef __bf16 bf16x4 __attribute__((ext_vector_type(4)));
typedef float f32x4 __attribute__((ext_vector_type(4)));
typedef short short4v __attribute__((ext_vector_type(4)));

#define BDIM_B 4
#define TDIM 2048
#define CDIM 1024

// -------- async global->LDS (16B per lane, wave-uniform LDS base + lane*16) -----
__device__ __forceinline__ void gload16(const void* g, void* l) {
  using GP = const __attribute__((address_space(1))) char*;
  using LP = __attribute__((address_space(3))) char*;
  __builtin_amdgcn_global_load_lds((GP)(uintptr_t)g, (LP)(uint32_t)(uintptr_t)l, 16, 0, 0);
}

// ---------------- weight transpose + fp32->bf16 cast:  Wt[n][k] = W[k][n] -------
__global__ __launch_bounds__(256)
void transpose_cast(const float* __restrict__ W, bf16_t* __restrict__ Wt, int K, int N) {
  __shared__ float tile[32][33];
  const int tx = threadIdx.x & 31, ty = threadIdx.x >> 5;  // 32 x 8
  const int n0 = blockIdx.x * 32, k0 = blockIdx.y * 32;
#pragma unroll
  for (int j = 0; j < 32; j += 8)
    tile[ty + j][tx] = W[(size_t)(k0 + ty + j) * N + n0 + tx];
  __syncthreads();
#pragma unroll
  for (int j = 0; j < 32; j += 8)
    Wt[(size_t)(n0 + ty + j) * K + k0 + tx] = (bf16_t)tile[tx][ty + j];
}

// ---------------- fused LayerNorm (fp32 in) -> bf16 out -------------------------
__global__ __launch_bounds__(256)
void ln_kernel(const float* __restrict__ x, const float* __restrict__ g,
               const float* __restrict__ bta, bf16_t* __restrict__ out) {
  const size_t row = blockIdx.x;
  const int tid = threadIdx.x;
  const float4 v = ((const float4*)(x + row * CDIM))[tid];
  float s = v.x + v.y + v.z + v.w;
#pragma unroll
  for (int off = 1; off < 64; off <<= 1) s += __shfl_xor(s, off);
  __shared__ float r1[4], r2[4];
  const int wv = tid >> 6, lane = tid & 63;
  if (!lane) r1[wv] = s;
  __syncthreads();
  const float mu = (r1[0] + r1[1] + r1[2] + r1[3]) * (1.f / CDIM);
  const float dx = v.x - mu, dy = v.y - mu, dz = v.z - mu, dw = v.w - mu;
  float q = dx * dx + dy * dy + dz * dz + dw * dw;
#pragma unroll
  for (int off = 1; off < 64; off <<= 1) q += __shfl_xor(q, off);
  if (!lane) r2[wv] = q;
  __syncthreads();
  const float var = (r2[0] + r2[1] + r2[2] + r2[3]) * (1.f / CDIM);
  const float rs = rsqrtf(var + 1e-5f);
  const float4 gg = ((const float4*)g)[tid];
  const float4 bb = ((const float4*)bta)[tid];
  bf16x4 o;
  o[0] = (bf16_t)(dx * rs * gg.x + bb.x);
  o[1] = (bf16_t)(dy * rs * gg.y + bb.y);
  o[2] = (bf16_t)(dz * rs * gg.z + bb.z);
  o[3] = (bf16_t)(dw * rs * gg.w + bb.w);
  ((bf16x4*)(out + row * CDIM))[tid] = o;
}

// ---------------- bf16 MFMA GEMM, Bt is N x K (k-contiguous) --------------------
// C[m][n] = sum_k A[m][k]*Bt[n][k] + bias[n] (+resid) (+gelu), 128x128 tile, BK=32
enum { EPI_BF16 = 0, EPI_RESID = 1, EPI_GELU = 2 };

template <int EPI>
__global__ __launch_bounds__(256)
void gemm_bt(const bf16_t* __restrict__ A, const bf16_t* __restrict__ Bt,
             const float* __restrict__ bias, const float* __restrict__ resid,
             void* __restrict__ outv, int M, int N, int K) {
  __shared__ bf16_t tA[128 * 32];
  __shared__ bf16_t tB[128 * 32];
  const int tid = threadIdx.x;
  const int lane = tid & 63;
  const int wv = tid >> 6;
  const int wr = wv >> 1, wc = wv & 1;
  const int rin = lane & 15, quad = lane >> 4;
  const int m0 = blockIdx.y * 128, n0 = blockIdx.x * 128;
  const int srow = lane >> 2, sseg = lane & 3;  // staging: 16 rows/wave-inst, 4x8 elem segs

  f32x4 acc[4][4] = {};

  for (int kt = 0; kt < K; kt += 32) {
    __syncthreads();
#pragma unroll
    for (int t = 0; t < 2; ++t) {
      const int inst = t * 4 + wv;
      const int row = inst * 16 + srow;
      gload16(A + (size_t)(m0 + row) * K + kt + sseg * 8, tA + inst * 512);
      gload16(Bt + (size_t)(n0 + row) * K + kt + sseg * 8, tB + inst * 512);
    }
    __syncthreads();
    bf16x8 af[4], bf[4];
#pragma unroll
    for (int i = 0; i < 4; ++i)
      af[i] = *(const bf16x8*)(tA + (wr * 64 + i * 16 + rin) * 32 + quad * 8);
#pragma unroll
    for (int i = 0; i < 4; ++i)
      bf[i] = *(const bf16x8*)(tB + (wc * 64 + i * 16 + rin) * 32 + quad * 8);
#pragma unroll
    for (int mi = 0; mi < 4; ++mi)
#pragma unroll
      for (int ni = 0; ni < 4; ++ni)
        acc[mi][ni] = __builtin_amdgcn_mfma_f32_16x16x32_bf16(af[mi], bf[ni], acc[mi][ni], 0, 0, 0);
  }

  // epilogue: C row = m0+wr*64+mi*16+quad*4+r ; col = n0+wc*64+ni*16+rin
  const int rbase = m0 + wr * 64 + quad * 4;
  const int cbase = n0 + wc * 64 + rin;
#pragma unroll
  for (int mi = 0; mi < 4; ++mi)
#pragma unroll
    for (int ni = 0; ni < 4; ++ni)
#pragma unroll
      for (int r = 0; r < 4; ++r) {
        const int m = rbase + mi * 16 + r;
        const int n = cbase + ni * 16;
        float v = acc[mi][ni][r] + bias[n];
        if (EPI == EPI_RESID) v += resid[(size_t)m * N + n];
        if (EPI == EPI_GELU) v = 0.5f * v * (1.0f + erff(v * 0.7071067811865476f));
        if (EPI == EPI_RESID)
          ((float*)outv)[(size_t)m * N + n] = v;
        else
          ((bf16_t*)outv)[(size_t)m * N + n] = (bf16_t)v;
      }
}

// ---------------- flash attention v3, causal, H=16 D=64 ------------------------
// Block: 128 q-rows, 4 waves x 32 rows. No max-subtraction (|logits| < ~4).
// S^T = K.Q^T so the score C-frag (lane=q, reg=key quad*4+r) IS the A-operand
// layout of mfma_f32_16x16x16bf16_1k -> PV straight from registers, no P LDS.
// Row-sum l via all-ones B-frag (its C reg r <-> q matches O's layout exactly).
// LOAD BALANCE: causal work per q-tile is 2*qt+2 k-tiles (2..32). A grid with
// one block per q-tile has no refill slack (1024 blocks = exactly resident
// capacity) and round-robin assignment aliases qt mod 16 onto the same CU ->
// 1.9x critical path, 11% occupancy. Fix: each block processes the PAIR
// (15-bx, bx) sequentially -> uniform 34 k-tiles per block, 512 equal blocks.
__global__ __launch_bounds__(256)
void attn_kernel(const bf16_t* __restrict__ qkv, bf16_t* __restrict__ y) {
  const int h = blockIdx.y, b = blockIdx.z;
  const int tid = threadIdx.x, lane = tid & 63, wv = tid >> 6;
  const int rin = lane & 15, quad = lane >> 4;

  __shared__ bf16_t Kt[64 * 64];  // K [t][d], row-group swizzled
  __shared__ bf16_t Vt[64 * 64];  // V^T [d][t], t-group swizzled per d

  const size_t base3 = (size_t)(b * TDIM) * 3072;
  const int srow = tid >> 2, sseg = tid & 3;
  const short4v ones = {(short)0x3F80, (short)0x3F80, (short)0x3F80, (short)0x3F80};

#pragma unroll 1
  for (int seg = 0; seg < 2; ++seg) {
    const int qt = seg ? blockIdx.x : (15 - blockIdx.x);  // long tile first
    const int q0 = qt * 128;
    const int nkt = qt * 2 + 2;

    // Q fragments direct from global (B-operand of S^T mfma: n=q=rin, k=d)
    bf16x8 aq[2][2];
#pragma unroll
    for (int qf = 0; qf < 2; ++qf) {
      const size_t qr = base3 + (size_t)(q0 + wv * 32 + qf * 16 + rin) * 3072 + h * 64;
#pragma unroll
      for (int ki = 0; ki < 2; ++ki)
        aq[qf][ki] = *(const bf16x8*)(qkv + qr + ki * 32 + quad * 8);
    }

    uint4 kreg[2], vreg[2];
#pragma unroll
    for (int hf = 0; hf < 2; ++hf) {  // prefetch kt=0
      const size_t gb = base3 + (size_t)srow * 3072 + h * 64 + hf * 32 + sseg * 8;
      kreg[hf] = *(const uint4*)(qkv + gb + 1024);
      vreg[hf] = *(const uint4*)(qkv + gb + 2048);
    }

    f32x4 o[2][4] = {};
    f32x4 ol[2] = {};  // row-sum accumulator (ones-column)

    for (int kt = 0; kt < nkt; ++kt) {
      __syncthreads();  // all waves done reading previous tiles
      {                 // staged regs -> LDS (swizzled)
        const int krot = (srow >> 2) & 7;
        const int tg = srow >> 3, to = srow & 7;
#pragma unroll
        for (int hf = 0; hf < 2; ++hf) {
          const int g = hf * 4 + sseg;
          *(uint4*)(Kt + srow * 64 + (((g + krot) & 7) * 8)) = kreg[hf];
          union { uint4 u; bf16_t e[8]; } vv;
          vv.u = vreg[hf];
#pragma unroll
          for (int j = 0; j < 8; ++j) {
            const int d = hf * 32 + sseg * 8 + j;
            Vt[d * 64 + (((tg + ((d >> 2) & 7)) & 7) * 8) + to] = vv.e[j];
          }
        }
      }
      __syncthreads();  // tiles ready
      {                 // prefetch next tile
        const int ktn = (kt + 1 < nkt) ? kt + 1 : kt;
#pragma unroll
        for (int hf = 0; hf < 2; ++hf) {
          const size_t gb = base3 + (size_t)(ktn * 64 + srow) * 3072 + h * 64 + hf * 32 + sseg * 8;
          kreg[hf] = *(const uint4*)(qkv + gb + 1024);
          vreg[hf] = *(const uint4*)(qkv + gb + 2048);
        }
      }
      // ---- S^T = K.Q^T : 16 MFMA (M=key, N=q)
      f32x4 st[2][4] = {};  // [qf][kf]
#pragma unroll
      for (int ki = 0; ki < 2; ++ki) {
        bf16x8 ak[4];
#pragma unroll
        for (int kf = 0; kf < 4; ++kf) {
          const int tr = kf * 16 + rin;
          ak[kf] = *(const bf16x8*)(Kt + tr * 64 + (((ki * 4 + quad + ((tr >> 2) & 7)) & 7) * 8));
        }
#pragma unroll
        for (int qf = 0; qf < 2; ++qf)
#pragma unroll
          for (int kf = 0; kf < 4; ++kf)
            st[qf][kf] = __builtin_amdgcn_mfma_f32_16x16x32_bf16(ak[kf], aq[qf][ki], st[qf][kf], 0, 0, 0);
      }
      // ---- softmax (no max-sub) + pack into A-frags of 16x16x16 (k=quad*4+r)
      const bool maskt = (kt >= 2 * qt);
      short4v pf[2][4];
#pragma unroll
      for (int qf = 0; qf < 2; ++qf) {
        const int qg = q0 + wv * 32 + qf * 16 + rin;
#pragma unroll
        for (int kf = 0; kf < 4; ++kf)
#pragma unroll
          for (int r = 0; r < 4; ++r) {
            const int kg = kt * 64 + kf * 16 + quad * 4 + r;
            float p = __builtin_amdgcn_exp2f(st[qf][kf][r] * 0.18033688f);
            if (maskt && kg > qg) p = 0.f;
            union { bf16_t bv; short sv; } cv;
            cv.bv = (bf16_t)p;
            pf[qf][kf][r] = cv.sv;
          }
      }
      // ---- PV + l : 40 MFMA 16x16x16, B-frags b64 from Vt, no P LDS traffic
#pragma unroll
      for (int kf = 0; kf < 4; ++kf) {
        short4v bv[4];
#pragma unroll
        for (int nd = 0; nd < 4; ++nd) {
          const int d = nd * 16 + rin;
          const int sw = (2 * kf + (quad >> 1) + ((d >> 2) & 7)) & 7;
          bv[nd] = *(const short4v*)(Vt + d * 64 + sw * 8 + (quad & 1) * 4);
        }
#pragma unroll
        for (int qf = 0; qf < 2; ++qf) {
#pragma unroll
          for (int nd = 0; nd < 4; ++nd)
            o[qf][nd] = __builtin_amdgcn_mfma_f32_16x16x16bf16_1k(pf[qf][kf], bv[nd], o[qf][nd], 0, 0, 0);
          ol[qf] = __builtin_amdgcn_mfma_f32_16x16x16bf16_1k(pf[qf][kf], ones, ol[qf], 0, 0, 0);
        }
      }
    }

    // ---- epilogue: O C-frag (lane=d, reg=q) and l frag (reg=q) align directly
#pragma unroll
    for (int qf = 0; qf < 2; ++qf)
#pragma unroll
      for (int r = 0; r < 4; ++r) {
        const float inv = 1.0f / ol[qf][r];
        const size_t row = (size_t)b * TDIM + q0 + wv * 32 + qf * 16 + quad * 4 + r;
#pragma unroll
        for (int nd = 0; nd < 4; ++nd)
          y[row * CDIM + h * 64 + nd * 16 + rin] = (bf16_t)(o[qf][nd][r] * inv);
      }
  }
}

extern "C" void kernel_launch(void* const* d_in, const int* in_sizes, int n_in,
                              void* d_out, int out_size, void* d_ws, size_t ws_size,
                              hipStream_t stream) {
  const float* x      = (const float*)d_in[0];
  const float* w_attn = (const float*)d_in[1];
  const float* b_attn = (const float*)d_in[2];
  const float* w_proj = (const float*)d_in[3];
  const float* b_proj = (const float*)d_in[4];
  const float* ln1g   = (const float*)d_in[5];
  const float* ln1b   = (const float*)d_in[6];
  const float* ln2g   = (const float*)d_in[7];
  const float* ln2b   = (const float*)d_in[8];
  const float* w_fc   = (const float*)d_in[9];
  const float* b_fc   = (const float*)d_in[10];
  const float* w_fc2  = (const float*)d_in[11];
  const float* b_fc2  = (const float*)d_in[12];
  float* out = (float*)d_out;

  char* ws = (char*)d_ws;
  bf16_t* wTattn = (bf16_t*)(ws + 0);                    //  6291456 B (3072x1024)
  bf16_t* wTproj = (bf16_t*)(ws + 6291456);              //  2097152 B (1024x1024)
  bf16_t* wTfc   = (bf16_t*)(ws + 8388608);              //  8388608 B (4096x1024)
  bf16_t* wTfc2  = (bf16_t*)(ws + 16777216);             //  8388608 B (1024x4096)
  bf16_t* xn     = (bf16_t*)(ws + 25165824);             // 16777216 B (8192x1024)
  float*  x2     = (float*)(ws + 41943040);              // 33554432 B (8192x1024)
  bf16_t* qkv    = (bf16_t*)(ws + 75497472);             // 50331648 B (8192x3072)
  bf16_t* yb     = (bf16_t*)(ws + 75497472 + 50331648);  // 16777216 B (8192x1024)
  bf16_t* hb     = (bf16_t*)(ws + 75497472);             // 67108864 B (8192x4096), reuses qkv+y

  // weights -> bf16 transposed
  transpose_cast<<<dim3(96, 32), 256, 0, stream>>>(w_attn, wTattn, 1024, 3072);
  transpose_cast<<<dim3(32, 32), 256, 0, stream>>>(w_proj, wTproj, 1024, 1024);
  transpose_cast<<<dim3(128, 32), 256, 0, stream>>>(w_fc, wTfc, 1024, 4096);
  transpose_cast<<<dim3(32, 128), 256, 0, stream>>>(w_fc2, wTfc2, 4096, 1024);

  // LN1 -> xn
  ln_kernel<<<8192, 256, 0, stream>>>(x, ln1g, ln1b, xn);
  // qkv = xn @ w_attn + b_attn   (bf16 out)
  gemm_bt<EPI_BF16><<<dim3(24, 64), 256, 0, stream>>>(xn, wTattn, b_attn, nullptr, qkv, 8192, 3072, 1024);
  // attention -> yb (bf16); paired q-tiles (15-bx, bx) for uniform causal work
  attn_kernel<<<dim3(8, 16, 4), 256, 0, stream>>>(qkv, yb);
  // x2 = x + yb @ w_proj + b_proj   (fp32)
  gemm_bt<EPI_RESID><<<dim3(8, 64), 256, 0, stream>>>(yb, wTproj, b_proj, x, x2, 8192, 1024, 1024);
  // LN2 -> xn
  ln_kernel<<<8192, 256, 0, stream>>>(x2, ln2g, ln2b, xn);
  // hb = gelu(xn @ w_fc + b_fc)   (bf16)
  gemm_bt<EPI_GELU><<<dim3(32, 64), 256, 0, stream>>>(xn, wTfc, b_fc, nullptr, hb, 8192, 4096, 1024);
  // out = x2 + hb @ w_fc2 + b_fc2  (fp32)
  gemm_bt<EPI_RESID><<<dim3(8, 64), 256, 0, stream>>>(hb, wTfc2, b_fc2, x2, out, 8192, 1024, 4096);
}

// Round 2
// 550.166 us; speedup vs baseline: 1.1431x; 1.0520x over previous
//
#include <hip/hip_runtime.h>
#include <hip/hip_bf16.h>
#include <stdint.h>

typedef __bf16 bf16_t;
typedef __bf16 bf16x8 __attribute__((ext_vector_type(8)));
typedef __bf16 bf16x4 __attribute__((ext_vector_type(4)));
typedef float f32x4 __attribute__((ext_vector_type(4)));
typedef short short4v __attribute__((ext_vector_type(4)));

#define BDIM_B 4
#define TDIM 2048
#define CDIM 1024

// -------- async global->LDS (16B per lane, wave-uniform LDS base + lane*16) -----
__device__ __forceinline__ void gload16(const void* g, void* l) {
  using GP = const __attribute__((address_space(1))) char*;
  using LP = __attribute__((address_space(3))) char*;
  __builtin_amdgcn_global_load_lds((GP)(uintptr_t)g, (LP)(uint32_t)(uintptr_t)l, 16, 0, 0);
}

// ---------------- weight transpose + fp32->bf16 cast:  Wt[n][k] = W[k][n] -------
__global__ __launch_bounds__(256)
void transpose_cast(const float* __restrict__ W, bf16_t* __restrict__ Wt, int K, int N) {
  __shared__ float tile[32][33];
  const int tx = threadIdx.x & 31, ty = threadIdx.x >> 5;  // 32 x 8
  const int n0 = blockIdx.x * 32, k0 = blockIdx.y * 32;
#pragma unroll
  for (int j = 0; j < 32; j += 8)
    tile[ty + j][tx] = W[(size_t)(k0 + ty + j) * N + n0 + tx];
  __syncthreads();
#pragma unroll
  for (int j = 0; j < 32; j += 8)
    Wt[(size_t)(n0 + ty + j) * K + k0 + tx] = (bf16_t)tile[tx][ty + j];
}

// ---------------- fused LayerNorm (fp32 in) -> bf16 out -------------------------
__global__ __launch_bounds__(256)
void ln_kernel(const float* __restrict__ x, const float* __restrict__ g,
               const float* __restrict__ bta, bf16_t* __restrict__ out) {
  const size_t row = blockIdx.x;
  const int tid = threadIdx.x;
  const float4 v = ((const float4*)(x + row * CDIM))[tid];
  float s = v.x + v.y + v.z + v.w;
#pragma unroll
  for (int off = 1; off < 64; off <<= 1) s += __shfl_xor(s, off);
  __shared__ float r1[4], r2[4];
  const int wv = tid >> 6, lane = tid & 63;
  if (!lane) r1[wv] = s;
  __syncthreads();
  const float mu = (r1[0] + r1[1] + r1[2] + r1[3]) * (1.f / CDIM);
  const float dx = v.x - mu, dy = v.y - mu, dz = v.z - mu, dw = v.w - mu;
  float q = dx * dx + dy * dy + dz * dz + dw * dw;
#pragma unroll
  for (int off = 1; off < 64; off <<= 1) q += __shfl_xor(q, off);
  if (!lane) r2[wv] = q;
  __syncthreads();
  const float var = (r2[0] + r2[1] + r2[2] + r2[3]) * (1.f / CDIM);
  const float rs = rsqrtf(var + 1e-5f);
  const float4 gg = ((const float4*)g)[tid];
  const float4 bb = ((const float4*)bta)[tid];
  bf16x4 o;
  o[0] = (bf16_t)(dx * rs * gg.x + bb.x);
  o[1] = (bf16_t)(dy * rs * gg.y + bb.y);
  o[2] = (bf16_t)(dz * rs * gg.z + bb.z);
  o[3] = (bf16_t)(dw * rs * gg.w + bb.w);
  ((bf16x4*)(out + row * CDIM))[tid] = o;
}

// ---------------- 256x256 8-wave counted-vmcnt MFMA GEMM ------------------------
// C[m][n] = sum_k A[m][k]*Bt[n][k] + bias[n] (+resid) (+gelu)
// BM=BN=256, BK=64, 512 threads (8 waves, 2x4), wave tile 128x64.
// Double-buffered LDS (128 KiB). Each wave stages only what it reads:
//   own A-half (128x64) in 4 rounds of 32 rows, own B-quarter (64x64) in 4
//   rounds of 16 rows. Per-tile issue groups: p0:{A0,B0,B1} p1:{A1,B2,B3}
//   p2:{A2} p3:{A3} -> per-phase fences vmcnt(5,5,7,7) retire exactly the
//   group staged one tile earlier. Never drains to 0 in the main loop (T4).
// LDS XOR swizzle: 16B chunk index ^= (row&7), applied on the pre-swizzled
// GLOBAL source (gload_lds writes linearly) and on the ds_read_b128 address
// -> 2 lanes per bank-group on fragment reads = conflict-free.
enum { EPI_BF16 = 0, EPI_RESID = 1, EPI_GELU = 2 };

template <int EPI>
__global__ __launch_bounds__(512)
void gemm256(const bf16_t* __restrict__ A, const bf16_t* __restrict__ Bt,
             const float* __restrict__ bias, const float* __restrict__ resid,
             void* __restrict__ outv, int M, int N, int K) {
  __shared__ bf16_t sA[2][256 * 64];
  __shared__ bf16_t sB[2][256 * 64];
  const int tid = threadIdx.x;
  const int lane = tid & 63, wv = tid >> 6;
  const int wm = wv >> 2, wn = wv & 3;
  const int rin = lane & 15, quad = lane >> 4;

  // XCD-aware bijective swizzle (all launches have nwg % 8 == 0)
  const int nwg = gridDim.x * gridDim.y;
  const int bid = blockIdx.y * gridDim.x + blockIdx.x;
  const int swzb = (bid & 7) * (nwg >> 3) + (bid >> 3);
  const int bx = swzb % gridDim.x, by = swzb / gridDim.x;
  const int m0 = by * 256, n0 = bx * 256;

  // ---- staging address constants (pre-swizzled global source, linear LDS dest)
  const int c8 = (lane & 7) ^ ((lane >> 3) & 7);             // chunk permutation
  const int aRow = wm * 128 + (wv & 3) * 8 + (lane >> 3);    // + 32*r
  const int bRow = wn * 64 + (wv >> 2) * 8 + (lane >> 3);    // + 16*r
  const bf16_t* srcA = A + (size_t)(m0 + aRow) * K + c8 * 8;
  const bf16_t* srcB = Bt + (size_t)(n0 + bRow) * K + c8 * 8;
  const int dstA = (wm * 128 + (wv & 3) * 8) * 64;           // + 32*r*64
  const int dstB = (wn * 64 + (wv >> 2) * 8) * 64;           // + 16*r*64

#define STA(buf, r, kk) gload16(srcA + (size_t)(32 * (r)) * K + (kk), (buf) + dstA + 32 * (r) * 64)
#define STB(buf, r, kk) gload16(srcB + (size_t)(16 * (r)) * K + (kk), (buf) + dstB + 16 * (r) * 64)

  // ---- fragment-read address constants (swizzled ds_read)
  const int ck0 = (quad ^ (rin & 7)) * 8;
  const int ck1 = ((4 + quad) ^ (rin & 7)) * 8;
  const int aBase = (wm * 128 + rin) * 64;
  const int bBase = (wn * 64 + rin) * 64;

  f32x4 acc[8][4] = {};
  bf16x8 af[8][2], bfr[4][2];

#define RDA(mi) { af[mi][0] = *(const bf16x8*)(rA + aBase + (mi)*1024 + ck0); \
                  af[mi][1] = *(const bf16x8*)(rA + aBase + (mi)*1024 + ck1); }
#define RDB(ni) { bfr[ni][0] = *(const bf16x8*)(rB + bBase + (ni)*1024 + ck0); \
                  bfr[ni][1] = *(const bf16x8*)(rB + bBase + (ni)*1024 + ck1); }
#define MM(mi, ni) { acc[mi][ni] = __builtin_amdgcn_mfma_f32_16x16x32_bf16(af[mi][0], bfr[ni][0], acc[mi][ni], 0, 0, 0); \
                     acc[mi][ni] = __builtin_amdgcn_mfma_f32_16x16x32_bf16(af[mi][1], bfr[ni][1], acc[mi][ni], 0, 0, 0); }

  const int NT = K >> 6;

  // ---- prologue: stage tile 0, same issue order as the loop body
  {
    bf16_t* wA = sA[0];
    bf16_t* wB = sB[0];
    STA(wA, 0, 0); STB(wB, 0, 0); STB(wB, 1, 0);
    STA(wA, 1, 0); STB(wB, 2, 0); STB(wB, 3, 0);
    STA(wA, 2, 0);
    STA(wA, 3, 0);
  }

  for (int t = 0; t < NT; ++t) {
    const bf16_t* rA = sA[t & 1];
    const bf16_t* rB = sB[t & 1];
    bf16_t* wA = sA[(t & 1) ^ 1];
    bf16_t* wB = sB[(t & 1) ^ 1];
    const int kk = (t + 1 < NT ? t + 1 : t) * 64;  // clamped prefetch (stray writes hit dead buffer)

    // ---- phase 0: needs A rows 0-31, B rows 0-31 of this tile
    asm volatile("s_waitcnt vmcnt(5)" ::: "memory");
    __builtin_amdgcn_s_barrier();
    __builtin_amdgcn_sched_barrier(0);
    RDA(0) RDA(1) RDB(0) RDB(1)
    STA(wA, 0, kk); STB(wB, 0, kk); STB(wB, 1, kk);
    __builtin_amdgcn_s_setprio(1);
    MM(0, 0) MM(0, 1) MM(1, 0) MM(1, 1)
    __builtin_amdgcn_s_setprio(0);
    __builtin_amdgcn_sched_barrier(0);

    // ---- phase 1: needs A rows 32-63, B rows 32-63
    asm volatile("s_waitcnt vmcnt(5)" ::: "memory");
    __builtin_amdgcn_s_barrier();
    __builtin_amdgcn_sched_barrier(0);
    RDA(2) RDA(3) RDB(2) RDB(3)
    STA(wA, 1, kk); STB(wB, 2, kk); STB(wB, 3, kk);
    __builtin_amdgcn_s_setprio(1);
    MM(0, 2) MM(0, 3) MM(1, 2) MM(1, 3) MM(2, 0) MM(2, 1) MM(3, 0) MM(3, 1)
    __builtin_amdgcn_s_setprio(0);
    __builtin_amdgcn_sched_barrier(0);

    // ---- phase 2: needs A rows 64-95
    asm volatile("s_waitcnt vmcnt(7)" ::: "memory");
    __builtin_amdgcn_s_barrier();
    __builtin_amdgcn_sched_barrier(0);
    RDA(4) RDA(5)
    STA(wA, 2, kk);
    __builtin_amdgcn_s_setprio(1);
    MM(2, 2) MM(2, 3) MM(3, 2) MM(3, 3) MM(4, 0) MM(4, 1) MM(5, 0) MM(5, 1)
    __builtin_amdgcn_s_setprio(0);
    __builtin_amdgcn_sched_barrier(0);

    // ---- phase 3 (+tail): needs A rows 96-127
    asm volatile("s_waitcnt vmcnt(7)" ::: "memory");
    __builtin_amdgcn_s_barrier();
    __builtin_amdgcn_sched_barrier(0);
    RDA(6) RDA(7)
    STA(wA, 3, kk);
    __builtin_amdgcn_s_setprio(1);
    MM(4, 2) MM(4, 3) MM(5, 2) MM(5, 3) MM(6, 0) MM(6, 1) MM(7, 0) MM(7, 1)
    MM(6, 2) MM(6, 3) MM(7, 2) MM(7, 3)
    __builtin_amdgcn_s_setprio(0);
    __builtin_amdgcn_sched_barrier(0);
  }
  asm volatile("s_waitcnt vmcnt(0)" ::: "memory");  // drain before LDS goes away

  // ---- epilogue: C row = m0+wm*128+mi*16+quad*4+r ; col = n0+wn*64+ni*16+rin
  const int rbase = m0 + wm * 128 + quad * 4;
  const int cbase = n0 + wn * 64 + rin;
#pragma unroll
  for (int mi = 0; mi < 8; ++mi)
#pragma unroll
    for (int ni = 0; ni < 4; ++ni)
#pragma unroll
      for (int r = 0; r < 4; ++r) {
        const int m = rbase + mi * 16 + r;
        const int n = cbase + ni * 16;
        float v = acc[mi][ni][r] + bias[n];
        if (EPI == EPI_RESID) v += resid[(size_t)m * N + n];
        if (EPI == EPI_GELU) v = 0.5f * v * (1.0f + erff(v * 0.7071067811865476f));
        if (EPI == EPI_RESID)
          ((float*)outv)[(size_t)m * N + n] = v;
        else
          ((bf16_t*)outv)[(size_t)m * N + n] = (bf16_t)v;
      }
#undef STA
#undef STB
#undef RDA
#undef RDB
#undef MM
}

// ---------------- flash attention v3, causal, H=16 D=64 ------------------------
// Block: 128 q-rows, 4 waves x 32 rows. No max-subtraction (|logits| < ~4).
// S^T = K.Q^T so the score C-frag (lane=q, reg=key quad*4+r) IS the A-operand
// layout of mfma_f32_16x16x16bf16_1k -> PV straight from registers, no P LDS.
// Row-sum l via all-ones B-frag (its C reg r <-> q matches O's layout exactly).
// Paired q-tiles (15-bx, bx) -> uniform 34 k-tiles per block, 512 equal blocks.
__global__ __launch_bounds__(256)
void attn_kernel(const bf16_t* __restrict__ qkv, bf16_t* __restrict__ y) {
  const int h = blockIdx.y, b = blockIdx.z;
  const int tid = threadIdx.x, lane = tid & 63, wv = tid >> 6;
  const int rin = lane & 15, quad = lane >> 4;

  __shared__ bf16_t Kt[64 * 64];  // K [t][d], row-group swizzled
  __shared__ bf16_t Vt[64 * 64];  // V^T [d][t], t-group swizzled per d

  const size_t base3 = (size_t)(b * TDIM) * 3072;
  const int srow = tid >> 2, sseg = tid & 3;
  const short4v ones = {(short)0x3F80, (short)0x3F80, (short)0x3F80, (short)0x3F80};

#pragma unroll 1
  for (int seg = 0; seg < 2; ++seg) {
    const int qt = seg ? blockIdx.x : (15 - blockIdx.x);  // long tile first
    const int q0 = qt * 128;
    const int nkt = qt * 2 + 2;

    // Q fragments direct from global (B-operand of S^T mfma: n=q=rin, k=d)
    bf16x8 aq[2][2];
#pragma unroll
    for (int qf = 0; qf < 2; ++qf) {
      const size_t qr = base3 + (size_t)(q0 + wv * 32 + qf * 16 + rin) * 3072 + h * 64;
#pragma unroll
      for (int ki = 0; ki < 2; ++ki)
        aq[qf][ki] = *(const bf16x8*)(qkv + qr + ki * 32 + quad * 8);
    }

    uint4 kreg[2], vreg[2];
#pragma unroll
    for (int hf = 0; hf < 2; ++hf) {  // prefetch kt=0
      const size_t gb = base3 + (size_t)srow * 3072 + h * 64 + hf * 32 + sseg * 8;
      kreg[hf] = *(const uint4*)(qkv + gb + 1024);
      vreg[hf] = *(const uint4*)(qkv + gb + 2048);
    }

    f32x4 o[2][4] = {};
    f32x4 ol[2] = {};  // row-sum accumulator (ones-column)

    for (int kt = 0; kt < nkt; ++kt) {
      __syncthreads();  // all waves done reading previous tiles
      {                 // staged regs -> LDS (swizzled)
        const int krot = (srow >> 2) & 7;
        const int tg = srow >> 3, to = srow & 7;
#pragma unroll
        for (int hf = 0; hf < 2; ++hf) {
          const int g = hf * 4 + sseg;
          *(uint4*)(Kt + srow * 64 + (((g + krot) & 7) * 8)) = kreg[hf];
          union { uint4 u; bf16_t e[8]; } vv;
          vv.u = vreg[hf];
#pragma unroll
          for (int j = 0; j < 8; ++j) {
            const int d = hf * 32 + sseg * 8 + j;
            Vt[d * 64 + (((tg + ((d >> 2) & 7)) & 7) * 8) + to] = vv.e[j];
          }
        }
      }
      __syncthreads();  // tiles ready
      {                 // prefetch next tile
        const int ktn = (kt + 1 < nkt) ? kt + 1 : kt;
#pragma unroll
        for (int hf = 0; hf < 2; ++hf) {
          const size_t gb = base3 + (size_t)(ktn * 64 + srow) * 3072 + h * 64 + hf * 32 + sseg * 8;
          kreg[hf] = *(const uint4*)(qkv + gb + 1024);
          vreg[hf] = *(const uint4*)(qkv + gb + 2048);
        }
      }
      // ---- S^T = K.Q^T : 16 MFMA (M=key, N=q)
      f32x4 st[2][4] = {};  // [qf][kf]
#pragma unroll
      for (int ki = 0; ki < 2; ++ki) {
        bf16x8 ak[4];
#pragma unroll
        for (int kf = 0; kf < 4; ++kf) {
          const int tr = kf * 16 + rin;
          ak[kf] = *(const bf16x8*)(Kt + tr * 64 + (((ki * 4 + quad + ((tr >> 2) & 7)) & 7) * 8));
        }
#pragma unroll
        for (int qf = 0; qf < 2; ++qf)
#pragma unroll
          for (int kf = 0; kf < 4; ++kf)
            st[qf][kf] = __builtin_amdgcn_mfma_f32_16x16x32_bf16(ak[kf], aq[qf][ki], st[qf][kf], 0, 0, 0);
      }
      // ---- softmax (no max-sub) + pack into A-frags of 16x16x16 (k=quad*4+r)
      const bool maskt = (kt >= 2 * qt);
      short4v pf[2][4];
#pragma unroll
      for (int qf = 0; qf < 2; ++qf) {
        const int qg = q0 + wv * 32 + qf * 16 + rin;
#pragma unroll
        for (int kf = 0; kf < 4; ++kf)
#pragma unroll
          for (int r = 0; r < 4; ++r) {
            const int kg = kt * 64 + kf * 16 + quad * 4 + r;
            float p = __builtin_amdgcn_exp2f(st[qf][kf][r] * 0.18033688f);
            if (maskt && kg > qg) p = 0.f;
            union { bf16_t bv; short sv; } cv;
            cv.bv = (bf16_t)p;
            pf[qf][kf][r] = cv.sv;
          }
      }
      // ---- PV + l : 40 MFMA 16x16x16, B-frags b64 from Vt, no P LDS traffic
#pragma unroll
      for (int kf = 0; kf < 4; ++kf) {
        short4v bv[4];
#pragma unroll
        for (int nd = 0; nd < 4; ++nd) {
          const int d = nd * 16 + rin;
          const int sw = (2 * kf + (quad >> 1) + ((d >> 2) & 7)) & 7;
          bv[nd] = *(const short4v*)(Vt + d * 64 + sw * 8 + (quad & 1) * 4);
        }
#pragma unroll
        for (int qf = 0; qf < 2; ++qf) {
#pragma unroll
          for (int nd = 0; nd < 4; ++nd)
            o[qf][nd] = __builtin_amdgcn_mfma_f32_16x16x16bf16_1k(pf[qf][kf], bv[nd], o[qf][nd], 0, 0, 0);
          ol[qf] = __builtin_amdgcn_mfma_f32_16x16x16bf16_1k(pf[qf][kf], ones, ol[qf], 0, 0, 0);
        }
      }
    }

    // ---- epilogue: O C-frag (lane=d, reg=q) and l frag (reg=q) align directly
#pragma unroll
    for (int qf = 0; qf < 2; ++qf)
#pragma unroll
      for (int r = 0; r < 4; ++r) {
        const float inv = 1.0f / ol[qf][r];
        const size_t row = (size_t)b * TDIM + q0 + wv * 32 + qf * 16 + quad * 4 + r;
#pragma unroll
        for (int nd = 0; nd < 4; ++nd)
          y[row * CDIM + h * 64 + nd * 16 + rin] = (bf16_t)(o[qf][nd][r] * inv);
      }
  }
}

extern "C" void kernel_launch(void* const* d_in, const int* in_sizes, int n_in,
                              void* d_out, int out_size, void* d_ws, size_t ws_size,
                              hipStream_t stream) {
  const float* x      = (const float*)d_in[0];
  const float* w_attn = (const float*)d_in[1];
  const float* b_attn = (const float*)d_in[2];
  const float* w_proj = (const float*)d_in[3];
  const float* b_proj = (const float*)d_in[4];
  const float* ln1g   = (const float*)d_in[5];
  const float* ln1b   = (const float*)d_in[6];
  const float* ln2g   = (const float*)d_in[7];
  const float* ln2b   = (const float*)d_in[8];
  const float* w_fc   = (const float*)d_in[9];
  const float* b_fc   = (const float*)d_in[10];
  const float* w_fc2  = (const float*)d_in[11];
  const float* b_fc2  = (const float*)d_in[12];
  float* out = (float*)d_out;

  char* ws = (char*)d_ws;
  bf16_t* wTattn = (bf16_t*)(ws + 0);                    //  6291456 B (3072x1024)
  bf16_t* wTproj = (bf16_t*)(ws + 6291456);              //  2097152 B (1024x1024)
  bf16_t* wTfc   = (bf16_t*)(ws + 8388608);              //  8388608 B (4096x1024)
  bf16_t* wTfc2  = (bf16_t*)(ws + 16777216);             //  8388608 B (1024x4096)
  bf16_t* xn     = (bf16_t*)(ws + 25165824);             // 16777216 B (8192x1024)
  float*  x2     = (float*)(ws + 41943040);              // 33554432 B (8192x1024)
  bf16_t* qkv    = (bf16_t*)(ws + 75497472);             // 50331648 B (8192x3072)
  bf16_t* yb     = (bf16_t*)(ws + 75497472 + 50331648);  // 16777216 B (8192x1024)
  bf16_t* hb     = (bf16_t*)(ws + 75497472);             // 67108864 B (8192x4096), reuses qkv+y

  // weights -> bf16 transposed
  transpose_cast<<<dim3(96, 32), 256, 0, stream>>>(w_attn, wTattn, 1024, 3072);
  transpose_cast<<<dim3(32, 32), 256, 0, stream>>>(w_proj, wTproj, 1024, 1024);
  transpose_cast<<<dim3(128, 32), 256, 0, stream>>>(w_fc, wTfc, 1024, 4096);
  transpose_cast<<<dim3(32, 128), 256, 0, stream>>>(w_fc2, wTfc2, 4096, 1024);

  // LN1 -> xn
  ln_kernel<<<8192, 256, 0, stream>>>(x, ln1g, ln1b, xn);
  // qkv = xn @ w_attn + b_attn   (bf16 out)
  gemm256<EPI_BF16><<<dim3(12, 32), 512, 0, stream>>>(xn, wTattn, b_attn, nullptr, qkv, 8192, 3072, 1024);
  // attention -> yb (bf16); paired q-tiles (15-bx, bx) for uniform causal work
  attn_kernel<<<dim3(8, 16, 4), 256, 0, stream>>>(qkv, yb);
  // x2 = x + yb @ w_proj + b_proj   (fp32)
  gemm256<EPI_RESID><<<dim3(4, 32), 512, 0, stream>>>(yb, wTproj, b_proj, x, x2, 8192, 1024, 1024);
  // LN2 -> xn
  ln_kernel<<<8192, 256, 0, stream>>>(x2, ln2g, ln2b, xn);
  // hb = gelu(xn @ w_fc + b_fc)   (bf16)
  gemm256<EPI_GELU><<<dim3(16, 32), 512, 0, stream>>>(xn, wTfc, b_fc, nullptr, hb, 8192, 4096, 1024);
  // out = x2 + hb @ w_fc2 + b_fc2  (fp32)
  gemm256<EPI_RESID><<<dim3(4, 32), 512, 0, stream>>>(hb, wTfc2, b_fc2, x2, out, 8192, 1024, 4096);
}

// Round 3
// 511.812 us; speedup vs baseline: 1.2288x; 1.0749x over previous
//
#include <hip/hip_runtime.h>
#include <hip/hip_bf16.h>
#include <stdint.h>

typedef __bf16 bf16_t;
typedef __bf16 bf16x8 __attribute__((ext_vector_type(8)));
typedef __bf16 bf16x4 __attribute__((ext_vector_type(4)));
typedef float f32x4 __attribute__((ext_vector_type(4)));
typedef short short4v __attribute__((ext_vector_type(4)));

#define BDIM_B 4
#define TDIM 2048
#define CDIM 1024

// -------- async global->LDS (16B per lane, wave-uniform LDS base + lane*16) -----
__device__ __forceinline__ void gload16(const void* g, void* l) {
  using GP = const __attribute__((address_space(1))) char*;
  using LP = __attribute__((address_space(3))) char*;
  __builtin_amdgcn_global_load_lds((GP)(uintptr_t)g, (LP)(uint32_t)(uintptr_t)l, 16, 0, 0);
}

#define S_BARRIER() asm volatile("s_barrier" ::: "memory")

// ---------------- weight transpose + fp32->bf16 cast:  Wt[n][k] = W[k][n] -------
__global__ __launch_bounds__(256)
void transpose_cast(const float* __restrict__ W, bf16_t* __restrict__ Wt, int K, int N) {
  __shared__ float tile[32][33];
  const int tx = threadIdx.x & 31, ty = threadIdx.x >> 5;  // 32 x 8
  const int n0 = blockIdx.x * 32, k0 = blockIdx.y * 32;
#pragma unroll
  for (int j = 0; j < 32; j += 8)
    tile[ty + j][tx] = W[(size_t)(k0 + ty + j) * N + n0 + tx];
  __syncthreads();
#pragma unroll
  for (int j = 0; j < 32; j += 8)
    Wt[(size_t)(n0 + ty + j) * K + k0 + tx] = (bf16_t)tile[tx][ty + j];
}

// ---------------- fused LayerNorm (fp32 in) -> bf16 out -------------------------
__global__ __launch_bounds__(256)
void ln_kernel(const float* __restrict__ x, const float* __restrict__ g,
               const float* __restrict__ bta, bf16_t* __restrict__ out) {
  const size_t row = blockIdx.x;
  const int tid = threadIdx.x;
  const float4 v = ((const float4*)(x + row * CDIM))[tid];
  float s = v.x + v.y + v.z + v.w;
#pragma unroll
  for (int off = 1; off < 64; off <<= 1) s += __shfl_xor(s, off);
  __shared__ float r1[4], r2[4];
  const int wv = tid >> 6, lane = tid & 63;
  if (!lane) r1[wv] = s;
  __syncthreads();
  const float mu = (r1[0] + r1[1] + r1[2] + r1[3]) * (1.f / CDIM);
  const float dx = v.x - mu, dy = v.y - mu, dz = v.z - mu, dw = v.w - mu;
  float q = dx * dx + dy * dy + dz * dz + dw * dw;
#pragma unroll
  for (int off = 1; off < 64; off <<= 1) q += __shfl_xor(q, off);
  if (!lane) r2[wv] = q;
  __syncthreads();
  const float var = (r2[0] + r2[1] + r2[2] + r2[3]) * (1.f / CDIM);
  const float rs = rsqrtf(var + 1e-5f);
  const float4 gg = ((const float4*)g)[tid];
  const float4 bb = ((const float4*)bta)[tid];
  bf16x4 o;
  o[0] = (bf16_t)(dx * rs * gg.x + bb.x);
  o[1] = (bf16_t)(dy * rs * gg.y + bb.y);
  o[2] = (bf16_t)(dz * rs * gg.z + bb.z);
  o[3] = (bf16_t)(dw * rs * gg.w + bb.w);
  ((bf16x4*)(out + row * CDIM))[tid] = o;
}

enum { EPI_BF16 = 0, EPI_RESID = 1, EPI_GELU = 2 };

// ---------------- 256x256 8-wave counted-vmcnt MFMA GEMM ------------------------
// BM=BN=256, BK=64, 512 threads (8 waves 2x4, wave tile 128x64), 2-buf LDS 128KiB.
// Phase structure: [ds_reads -> counted vmcnt fence -> s_barrier -> stage-issue ->
// setprio MFMA]. ds_reads issued PRE-barrier so barrier-wait hides LDS latency.
// Stage issues POST-barrier: race-free vs other waves' in-flight reads of the
// target buffer (they retired before reaching this barrier). Fences per phase
// retire exactly the loads the NEXT phase reads; never drain to 0 in the loop.
// LDS chunk-XOR swizzle (c ^= row&7) on pre-swizzled global src + swizzled
// ds_read -> conflict-free b128 reads. No sched_barrier(0) (m141: it regresses).
template <int EPI>
__global__ __launch_bounds__(512)
void gemm256(const bf16_t* __restrict__ A, const bf16_t* __restrict__ Bt,
             const float* __restrict__ bias, const float* __restrict__ resid,
             void* __restrict__ outv, int M, int N, int K) {
  __shared__ bf16_t sA[2][256 * 64];
  __shared__ bf16_t sB[2][256 * 64];
  const int tid = threadIdx.x;
  const int lane = tid & 63, wv = tid >> 6;
  const int wm = wv >> 2, wn = wv & 3;
  const int rin = lane & 15, quad = lane >> 4;

  // XCD-aware bijective swizzle (nwg % 8 == 0 for all launches)
  const int nwg = gridDim.x * gridDim.y;
  const int bid = blockIdx.y * gridDim.x + blockIdx.x;
  const int swzb = (bid & 7) * (nwg >> 3) + (bid >> 3);
  const int bx = swzb % gridDim.x, by = swzb / gridDim.x;
  const int m0 = by * 256, n0 = bx * 256;

  // staging: pre-swizzled global source, linear LDS dest
  const int c8 = (lane & 7) ^ ((lane >> 3) & 7);
  const int aRow = wm * 128 + (wv & 3) * 8 + (lane >> 3);  // + 32*r
  const int bRow = wn * 64 + (wv >> 2) * 8 + (lane >> 3);  // + 16*r
  const bf16_t* srcA = A + (size_t)(m0 + aRow) * K + c8 * 8;
  const bf16_t* srcB = Bt + (size_t)(n0 + bRow) * K + c8 * 8;
  const int dstA = (wm * 128 + (wv & 3) * 8) * 64;
  const int dstB = (wn * 64 + (wv >> 2) * 8) * 64;

#define STA(buf, r, kk) gload16(srcA + (size_t)(32 * (r)) * K + (kk), (buf) + dstA + 32 * (r) * 64)
#define STB(buf, r, kk) gload16(srcB + (size_t)(16 * (r)) * K + (kk), (buf) + dstB + 16 * (r) * 64)

  // fragment reads (swizzled)
  const int ck0 = (quad ^ (rin & 7)) * 8;
  const int ck1 = ((4 + quad) ^ (rin & 7)) * 8;
  const int aBase = (wm * 128 + rin) * 64;
  const int bBase = (wn * 64 + rin) * 64;

  f32x4 acc[8][4] = {};
  bf16x8 af[8][2], bfr[4][2];

#define RDA(mi) { af[mi][0] = *(const bf16x8*)(rA + aBase + (mi)*1024 + ck0); \
                  af[mi][1] = *(const bf16x8*)(rA + aBase + (mi)*1024 + ck1); }
#define RDB(ni) { bfr[ni][0] = *(const bf16x8*)(rB + bBase + (ni)*1024 + ck0); \
                  bfr[ni][1] = *(const bf16x8*)(rB + bBase + (ni)*1024 + ck1); }
#define MM(mi, ni) { acc[mi][ni] = __builtin_amdgcn_mfma_f32_16x16x32_bf16(af[mi][0], bfr[ni][0], acc[mi][ni], 0, 0, 0); \
                     acc[mi][ni] = __builtin_amdgcn_mfma_f32_16x16x32_bf16(af[mi][1], bfr[ni][1], acc[mi][ni], 0, 0, 0); }

  const int NT = K >> 6;

  // prologue: stage tile 0 (order a0,b0,b1 | a1,b2,b3 | a2 | a3)
  STA(sA[0], 0, 0); STB(sB[0], 0, 0); STB(sB[0], 1, 0);
  STA(sA[0], 1, 0); STB(sB[0], 2, 0); STB(sB[0], 3, 0);
  STA(sA[0], 2, 0);
  STA(sA[0], 3, 0);
  asm volatile("s_waitcnt vmcnt(5)" ::: "memory");  // tile0 {a0,b0,b1} landed
  S_BARRIER();

  for (int t = 0; t < NT; ++t) {
    const bf16_t* rA = sA[t & 1];
    const bf16_t* rB = sB[t & 1];
    bf16_t* wA = sA[(t & 1) ^ 1];
    bf16_t* wB = sB[(t & 1) ^ 1];
    const int kk = (t + 1 < NT ? t + 1 : t) * 64;  // clamp: stray reload hits dead buffer

    // phase 0: reads A rows 0-31, B rows 0-31 (guaranteed by prev fence+barrier)
    RDA(0) RDA(1) RDB(0) RDB(1)
    asm volatile("s_waitcnt vmcnt(2)" ::: "memory");  // this tile {a1,b2,b3}
    S_BARRIER();
    STA(wA, 0, kk); STB(wB, 0, kk); STB(wB, 1, kk);
    __builtin_amdgcn_s_setprio(1);
    MM(0, 0) MM(0, 1) MM(1, 0) MM(1, 1)
    __builtin_amdgcn_s_setprio(0);

    // phase 1: reads A rows 32-63, B rows 32-63
    RDA(2) RDA(3) RDB(2) RDB(3)
    asm volatile("s_waitcnt vmcnt(4)" ::: "memory");  // this tile {a2}
    S_BARRIER();
    STA(wA, 1, kk); STB(wB, 2, kk); STB(wB, 3, kk);
    __builtin_amdgcn_s_setprio(1);
    MM(0, 2) MM(0, 3) MM(1, 2) MM(1, 3) MM(2, 0) MM(2, 1) MM(3, 0) MM(3, 1)
    __builtin_amdgcn_s_setprio(0);

    // phase 2: reads A rows 64-95
    RDA(4) RDA(5)
    asm volatile("s_waitcnt vmcnt(6)" ::: "memory");  // this tile {a3}
    S_BARRIER();
    STA(wA, 2, kk);
    __builtin_amdgcn_s_setprio(1);
    MM(2, 2) MM(2, 3) MM(3, 2) MM(3, 3) MM(4, 0) MM(4, 1) MM(5, 0) MM(5, 1)
    __builtin_amdgcn_s_setprio(0);

    // phase 3: reads A rows 96-127
    RDA(6) RDA(7)
    asm volatile("s_waitcnt vmcnt(4)" ::: "memory");  // next tile {a0,b0,b1}
    S_BARRIER();
    STA(wA, 3, kk);
    __builtin_amdgcn_s_setprio(1);
    MM(4, 2) MM(4, 3) MM(5, 2) MM(5, 3) MM(6, 0) MM(6, 1) MM(7, 0) MM(7, 1)
    MM(6, 2) MM(6, 3) MM(7, 2) MM(7, 3)
    __builtin_amdgcn_s_setprio(0);
  }
  asm volatile("s_waitcnt vmcnt(0)" ::: "memory");  // drain strays

  const int rbase = m0 + wm * 128 + quad * 4;
  const int cbase = n0 + wn * 64 + rin;
#pragma unroll
  for (int mi = 0; mi < 8; ++mi)
#pragma unroll
    for (int ni = 0; ni < 4; ++ni)
#pragma unroll
      for (int r = 0; r < 4; ++r) {
        const int m = rbase + mi * 16 + r;
        const int n = cbase + ni * 16;
        float v = acc[mi][ni][r] + bias[n];
        if (EPI == EPI_RESID) v += resid[(size_t)m * N + n];
        if (EPI == EPI_GELU) v = 0.5f * v * (1.0f + erff(v * 0.7071067811865476f));
        if (EPI == EPI_RESID)
          ((float*)outv)[(size_t)m * N + n] = v;
        else
          ((bf16_t*)outv)[(size_t)m * N + n] = (bf16_t)v;
      }
#undef STA
#undef STB
#undef RDA
#undef RDB
#undef MM
}

// ---------------- 256x128 8-wave ring-3 MFMA GEMM (for N=1024 / qkv grids) ------
// BM=256, BN=128, BK=64, 8 waves 4x2 (wave tile 64x64), 3-buf LDS ring 144KiB.
// Stage 2 tiles ahead -> fences stay at vmcnt(6) (deep pipeline). 2 phases/tile.
// Same [RD -> fence -> barrier -> stage -> MFMA] discipline as gemm256.
template <int EPI>
__global__ __launch_bounds__(512)
void gemm128(const bf16_t* __restrict__ A, const bf16_t* __restrict__ Bt,
             const float* __restrict__ bias, const float* __restrict__ resid,
             void* __restrict__ outv, int M, int N, int K) {
  __shared__ bf16_t sA[3][256 * 64];  // 96 KiB
  __shared__ bf16_t sB[3][128 * 64];  // 48 KiB
  const int tid = threadIdx.x;
  const int lane = tid & 63, wv = tid >> 6;
  const int wm = wv >> 1, wn = wv & 1;
  const int rin = lane & 15, quad = lane >> 4;

  const int nwg = gridDim.x * gridDim.y;
  const int bid = blockIdx.y * gridDim.x + blockIdx.x;
  const int swzb = (bid & 7) * (nwg >> 3) + (bid >> 3);
  const int bx = swzb % gridDim.x, by = swzb / gridDim.x;
  const int m0 = by * 256, n0 = bx * 128;

  const int c8 = (lane & 7) ^ ((lane >> 3) & 7);
  // A: 4 rounds x 64 rows, all 8 waves; round r rows = 64r + 8*wv + lane>>3
  const bf16_t* srcA = A + (size_t)(m0 + 8 * wv + (lane >> 3)) * K + c8 * 8;
  const int dstA = (8 * wv) * 64;
  // B: 2 rounds x 64 rows; round r rows = (wv>>2)*64 + 32r + (wv&3)*8 + lane>>3
  const bf16_t* srcB = Bt + (size_t)(n0 + (wv >> 2) * 64 + (wv & 3) * 8 + (lane >> 3)) * K + c8 * 8;
  const int dstB = ((wv >> 2) * 64 + (wv & 3) * 8) * 64;

#define STA(buf, r, kk) gload16(srcA + (size_t)(64 * (r)) * K + (kk), (buf) + dstA + 64 * (r) * 64)
#define STB(buf, r, kk) gload16(srcB + (size_t)(32 * (r)) * K + (kk), (buf) + dstB + 32 * (r) * 64)

  const int ck0 = (quad ^ (rin & 7)) * 8;
  const int ck1 = ((4 + quad) ^ (rin & 7)) * 8;
  const int aBase = (wm * 64 + rin) * 64;
  const int bBase = (wn * 64 + rin) * 64;

  f32x4 acc[4][4] = {};
  bf16x8 af[4][2], bfr[4][2];

#define RDA(mi) { af[mi][0] = *(const bf16x8*)(rA + aBase + (mi)*1024 + ck0); \
                  af[mi][1] = *(const bf16x8*)(rA + aBase + (mi)*1024 + ck1); }
#define RDB(ni) { bfr[ni][0] = *(const bf16x8*)(rB + bBase + (ni)*1024 + ck0); \
                  bfr[ni][1] = *(const bf16x8*)(rB + bBase + (ni)*1024 + ck1); }
#define MM(mi, ni) { acc[mi][ni] = __builtin_amdgcn_mfma_f32_16x16x32_bf16(af[mi][0], bfr[ni][0], acc[mi][ni], 0, 0, 0); \
                     acc[mi][ni] = __builtin_amdgcn_mfma_f32_16x16x32_bf16(af[mi][1], bfr[ni][1], acc[mi][ni], 0, 0, 0); }

  const int NT = K >> 6;

  // prologue: stage tiles 0,1 (order a0..a3,b0 | b1)
  STA(sA[0], 0, 0); STA(sA[0], 1, 0); STA(sA[0], 2, 0); STA(sA[0], 3, 0); STB(sB[0], 0, 0);
  STB(sB[0], 1, 0);
  STA(sA[1], 0, 64); STA(sA[1], 1, 64); STA(sA[1], 2, 64); STA(sA[1], 3, 64); STB(sB[1], 0, 64);
  STB(sB[1], 1, 64);
  asm volatile("s_waitcnt vmcnt(7)" ::: "memory");  // tile0 {a0..a3,b0} landed
  S_BARRIER();

  int rb = 0, wb = 2;
  for (int t = 0; t < NT; ++t) {
    const bf16_t* rA = sA[rb];
    const bf16_t* rB = sB[rb];
    bf16_t* wA = sA[wb];
    bf16_t* wB = sB[wb];
    const int kk = (t + 2 < NT ? t + 2 : NT - 1) * 64;  // clamp: target buf never read again

    // phase 0: all A rows + B rows {0-31 of each half}
    RDA(0) RDA(1) RDA(2) RDA(3) RDB(0) RDB(1)
    asm volatile("s_waitcnt vmcnt(6)" ::: "memory");  // this tile {b1}
    S_BARRIER();
    STA(wA, 0, kk); STA(wA, 1, kk); STA(wA, 2, kk); STA(wA, 3, kk); STB(wB, 0, kk);
    __builtin_amdgcn_s_setprio(1);
    MM(0, 0) MM(0, 1) MM(1, 0) MM(1, 1) MM(2, 0) MM(2, 1) MM(3, 0) MM(3, 1)
    __builtin_amdgcn_s_setprio(0);

    // phase 1: B rows {32-63 of each half}
    RDB(2) RDB(3)
    asm volatile("s_waitcnt vmcnt(6)" ::: "memory");  // next tile {a0..a3,b0}
    S_BARRIER();
    STB(wB, 1, kk);
    __builtin_amdgcn_s_setprio(1);
    MM(0, 2) MM(0, 3) MM(1, 2) MM(1, 3) MM(2, 2) MM(2, 3) MM(3, 2) MM(3, 3)
    __builtin_amdgcn_s_setprio(0);

    rb = (rb == 2) ? 0 : rb + 1;
    wb = (wb == 2) ? 0 : wb + 1;
  }
  asm volatile("s_waitcnt vmcnt(0)" ::: "memory");

  const int rbase = m0 + wm * 64 + quad * 4;
  const int cbase = n0 + wn * 64 + rin;
#pragma unroll
  for (int mi = 0; mi < 4; ++mi)
#pragma unroll
    for (int ni = 0; ni < 4; ++ni)
#pragma unroll
      for (int r = 0; r < 4; ++r) {
        const int m = rbase + mi * 16 + r;
        const int n = cbase + ni * 16;
        float v = acc[mi][ni][r] + bias[n];
        if (EPI == EPI_RESID) v += resid[(size_t)m * N + n];
        if (EPI == EPI_GELU) v = 0.5f * v * (1.0f + erff(v * 0.7071067811865476f));
        if (EPI == EPI_RESID)
          ((float*)outv)[(size_t)m * N + n] = v;
        else
          ((bf16_t*)outv)[(size_t)m * N + n] = (bf16_t)v;
      }
#undef STA
#undef STB
#undef RDA
#undef RDB
#undef MM
}

// ---------------- flash attention v3, causal, H=16 D=64 ------------------------
// Paired q-tiles (15-bx, bx) -> uniform 34 k-tiles per block, 512 equal blocks.
__global__ __launch_bounds__(256)
void attn_kernel(const bf16_t* __restrict__ qkv, bf16_t* __restrict__ y) {
  const int h = blockIdx.y, b = blockIdx.z;
  const int tid = threadIdx.x, lane = tid & 63, wv = tid >> 6;
  const int rin = lane & 15, quad = lane >> 4;

  __shared__ bf16_t Kt[64 * 64];  // K [t][d], row-group swizzled
  __shared__ bf16_t Vt[64 * 64];  // V^T [d][t], t-group swizzled per d

  const size_t base3 = (size_t)(b * TDIM) * 3072;
  const int srow = tid >> 2, sseg = tid & 3;
  const short4v ones = {(short)0x3F80, (short)0x3F80, (short)0x3F80, (short)0x3F80};

#pragma unroll 1
  for (int seg = 0; seg < 2; ++seg) {
    const int qt = seg ? blockIdx.x : (15 - blockIdx.x);  // long tile first
    const int q0 = qt * 128;
    const int nkt = qt * 2 + 2;

    bf16x8 aq[2][2];
#pragma unroll
    for (int qf = 0; qf < 2; ++qf) {
      const size_t qr = base3 + (size_t)(q0 + wv * 32 + qf * 16 + rin) * 3072 + h * 64;
#pragma unroll
      for (int ki = 0; ki < 2; ++ki)
        aq[qf][ki] = *(const bf16x8*)(qkv + qr + ki * 32 + quad * 8);
    }

    uint4 kreg[2], vreg[2];
#pragma unroll
    for (int hf = 0; hf < 2; ++hf) {  // prefetch kt=0
      const size_t gb = base3 + (size_t)srow * 3072 + h * 64 + hf * 32 + sseg * 8;
      kreg[hf] = *(const uint4*)(qkv + gb + 1024);
      vreg[hf] = *(const uint4*)(qkv + gb + 2048);
    }

    f32x4 o[2][4] = {};
    f32x4 ol[2] = {};

    for (int kt = 0; kt < nkt; ++kt) {
      __syncthreads();
      {  // staged regs -> LDS (swizzled)
        const int krot = (srow >> 2) & 7;
        const int tg = srow >> 3, to = srow & 7;
#pragma unroll
        for (int hf = 0; hf < 2; ++hf) {
          const int g = hf * 4 + sseg;
          *(uint4*)(Kt + srow * 64 + (((g + krot) & 7) * 8)) = kreg[hf];
          union { uint4 u; bf16_t e[8]; } vv;
          vv.u = vreg[hf];
#pragma unroll
          for (int j = 0; j < 8; ++j) {
            const int d = hf * 32 + sseg * 8 + j;
            Vt[d * 64 + (((tg + ((d >> 2) & 7)) & 7) * 8) + to] = vv.e[j];
          }
        }
      }
      __syncthreads();
      {  // prefetch next tile
        const int ktn = (kt + 1 < nkt) ? kt + 1 : kt;
#pragma unroll
        for (int hf = 0; hf < 2; ++hf) {
          const size_t gb = base3 + (size_t)(ktn * 64 + srow) * 3072 + h * 64 + hf * 32 + sseg * 8;
          kreg[hf] = *(const uint4*)(qkv + gb + 1024);
          vreg[hf] = *(const uint4*)(qkv + gb + 2048);
        }
      }
      // S^T = K.Q^T
      f32x4 st[2][4] = {};
#pragma unroll
      for (int ki = 0; ki < 2; ++ki) {
        bf16x8 ak[4];
#pragma unroll
        for (int kf = 0; kf < 4; ++kf) {
          const int tr = kf * 16 + rin;
          ak[kf] = *(const bf16x8*)(Kt + tr * 64 + (((ki * 4 + quad + ((tr >> 2) & 7)) & 7) * 8));
        }
#pragma unroll
        for (int qf = 0; qf < 2; ++qf)
#pragma unroll
          for (int kf = 0; kf < 4; ++kf)
            st[qf][kf] = __builtin_amdgcn_mfma_f32_16x16x32_bf16(ak[kf], aq[qf][ki], st[qf][kf], 0, 0, 0);
      }
      // softmax (no max-sub) + pack
      const bool maskt = (kt >= 2 * qt);
      short4v pf[2][4];
#pragma unroll
      for (int qf = 0; qf < 2; ++qf) {
        const int qg = q0 + wv * 32 + qf * 16 + rin;
#pragma unroll
        for (int kf = 0; kf < 4; ++kf)
#pragma unroll
          for (int r = 0; r < 4; ++r) {
            const int kg = kt * 64 + kf * 16 + quad * 4 + r;
            float p = __builtin_amdgcn_exp2f(st[qf][kf][r] * 0.18033688f);
            if (maskt && kg > qg) p = 0.f;
            union { bf16_t bv; short sv; } cv;
            cv.bv = (bf16_t)p;
            pf[qf][kf][r] = cv.sv;
          }
      }
      // PV + l
#pragma unroll
      for (int kf = 0; kf < 4; ++kf) {
        short4v bv[4];
#pragma unroll
        for (int nd = 0; nd < 4; ++nd) {
          const int d = nd * 16 + rin;
          const int sw = (2 * kf + (quad >> 1) + ((d >> 2) & 7)) & 7;
          bv[nd] = *(const short4v*)(Vt + d * 64 + sw * 8 + (quad & 1) * 4);
        }
#pragma unroll
        for (int qf = 0; qf < 2; ++qf) {
#pragma unroll
          for (int nd = 0; nd < 4; ++nd)
            o[qf][nd] = __builtin_amdgcn_mfma_f32_16x16x16bf16_1k(pf[qf][kf], bv[nd], o[qf][nd], 0, 0, 0);
          ol[qf] = __builtin_amdgcn_mfma_f32_16x16x16bf16_1k(pf[qf][kf], ones, ol[qf], 0, 0, 0);
        }
      }
    }

#pragma unroll
    for (int qf = 0; qf < 2; ++qf)
#pragma unroll
      for (int r = 0; r < 4; ++r) {
        const float inv = 1.0f / ol[qf][r];
        const size_t row = (size_t)b * TDIM + q0 + wv * 32 + qf * 16 + quad * 4 + r;
#pragma unroll
        for (int nd = 0; nd < 4; ++nd)
          y[row * CDIM + h * 64 + nd * 16 + rin] = (bf16_t)(o[qf][nd][r] * inv);
      }
  }
}

extern "C" void kernel_launch(void* const* d_in, const int* in_sizes, int n_in,
                              void* d_out, int out_size, void* d_ws, size_t ws_size,
                              hipStream_t stream) {
  const float* x      = (const float*)d_in[0];
  const float* w_attn = (const float*)d_in[1];
  const float* b_attn = (const float*)d_in[2];
  const float* w_proj = (const float*)d_in[3];
  const float* b_proj = (const float*)d_in[4];
  const float* ln1g   = (const float*)d_in[5];
  const float* ln1b   = (const float*)d_in[6];
  const float* ln2g   = (const float*)d_in[7];
  const float* ln2b   = (const float*)d_in[8];
  const float* w_fc   = (const float*)d_in[9];
  const float* b_fc   = (const float*)d_in[10];
  const float* w_fc2  = (const float*)d_in[11];
  const float* b_fc2  = (const float*)d_in[12];
  float* out = (float*)d_out;

  char* ws = (char*)d_ws;
  bf16_t* wTattn = (bf16_t*)(ws + 0);                    //  6291456 B (3072x1024)
  bf16_t* wTproj = (bf16_t*)(ws + 6291456);              //  2097152 B (1024x1024)
  bf16_t* wTfc   = (bf16_t*)(ws + 8388608);              //  8388608 B (4096x1024)
  bf16_t* wTfc2  = (bf16_t*)(ws + 16777216);             //  8388608 B (1024x4096)
  bf16_t* xn     = (bf16_t*)(ws + 25165824);             // 16777216 B (8192x1024)
  float*  x2     = (float*)(ws + 41943040);              // 33554432 B (8192x1024)
  bf16_t* qkv    = (bf16_t*)(ws + 75497472);             // 50331648 B (8192x3072)
  bf16_t* yb     = (bf16_t*)(ws + 75497472 + 50331648);  // 16777216 B (8192x1024)
  bf16_t* hb     = (bf16_t*)(ws + 75497472);             // 67108864 B (8192x4096), reuses qkv+y

  // weights -> bf16 transposed
  transpose_cast<<<dim3(96, 32), 256, 0, stream>>>(w_attn, wTattn, 1024, 3072);
  transpose_cast<<<dim3(32, 32), 256, 0, stream>>>(w_proj, wTproj, 1024, 1024);
  transpose_cast<<<dim3(128, 32), 256, 0, stream>>>(w_fc, wTfc, 1024, 4096);
  transpose_cast<<<dim3(32, 128), 256, 0, stream>>>(w_fc2, wTfc2, 4096, 1024);

  // LN1 -> xn
  ln_kernel<<<8192, 256, 0, stream>>>(x, ln1g, ln1b, xn);
  // qkv = xn @ w_attn + b_attn   (bf16 out), 768 blocks = 3 full rounds
  gemm128<EPI_BF16><<<dim3(24, 32), 512, 0, stream>>>(xn, wTattn, b_attn, nullptr, qkv, 8192, 3072, 1024);
  // attention -> yb
  attn_kernel<<<dim3(8, 16, 4), 256, 0, stream>>>(qkv, yb);
  // x2 = x + yb @ w_proj + b_proj (fp32), 256 blocks = full machine
  gemm128<EPI_RESID><<<dim3(8, 32), 512, 0, stream>>>(yb, wTproj, b_proj, x, x2, 8192, 1024, 1024);
  // LN2 -> xn
  ln_kernel<<<8192, 256, 0, stream>>>(x2, ln2g, ln2b, xn);
  // hb = gelu(xn @ w_fc + b_fc)  (bf16), 512 blocks = 2 full rounds
  gemm256<EPI_GELU><<<dim3(16, 32), 512, 0, stream>>>(xn, wTfc, b_fc, nullptr, hb, 8192, 4096, 1024);
  // out = x2 + hb @ w_fc2 + b_fc2 (fp32), 256 blocks = full machine
  gemm128<EPI_RESID><<<dim3(8, 32), 512, 0, stream>>>(hb, wTfc2, b_fc2, x2, out, 8192, 1024, 4096);
}

// Round 5
// 465.278 us; speedup vs baseline: 1.3517x; 1.1000x over previous
//
#include <hip/hip_runtime.h>
#include <hip/hip_bf16.h>
#include <stdint.h>

typedef __bf16 bf16_t;
typedef __bf16 bf16x8 __attribute__((ext_vector_type(8)));
typedef __bf16 bf16x4 __attribute__((ext_vector_type(4)));
typedef float f32x4 __attribute__((ext_vector_type(4)));
typedef short short4v __attribute__((ext_vector_type(4)));

#define BDIM_B 4
#define TDIM 2048
#define CDIM 1024

// -------- async global->LDS (16B per lane, wave-uniform LDS base + lane*16) -----
__device__ __forceinline__ void gload16(const void* g, void* l) {
  using GP = const __attribute__((address_space(1))) char*;
  using LP = __attribute__((address_space(3))) char*;
  __builtin_amdgcn_global_load_lds((GP)(uintptr_t)g, (LP)(uint32_t)(uintptr_t)l, 16, 0, 0);
}

#define S_BARRIER() asm volatile("s_barrier" ::: "memory")

// ---------------- weight transpose + fp32->bf16 cast:  Wt[n][k] = W[k][n] -------
__global__ __launch_bounds__(256)
void transpose_cast(const float* __restrict__ W, bf16_t* __restrict__ Wt, int K, int N) {
  __shared__ float tile[32][33];
  const int tx = threadIdx.x & 31, ty = threadIdx.x >> 5;  // 32 x 8
  const int n0 = blockIdx.x * 32, k0 = blockIdx.y * 32;
#pragma unroll
  for (int j = 0; j < 32; j += 8)
    tile[ty + j][tx] = W[(size_t)(k0 + ty + j) * N + n0 + tx];
  __syncthreads();
#pragma unroll
  for (int j = 0; j < 32; j += 8)
    Wt[(size_t)(n0 + ty + j) * K + k0 + tx] = (bf16_t)tile[tx][ty + j];
}

// ---------------- V pre-transpose: vT[b][h][d][t] = qkv V-part ------------------
__global__ __launch_bounds__(256)
void transpose_v(const bf16_t* __restrict__ qkv, bf16_t* __restrict__ vT) {
  __shared__ bf16_t tile[64 * 64];
  const int tt = blockIdx.x;  // t0 = tt*64
  const int h = blockIdx.y, b = blockIdx.z;
  const int tid = threadIdx.x;
  const int sr = tid >> 3, sc = tid & 7;
  const bf16_t* src = qkv + (size_t)(b * TDIM) * 3072 + 2048 + h * 64;
#pragma unroll
  for (int p = 0; p < 2; ++p) {
    const int t = p * 32 + sr;
    *(uint4*)(tile + t * 64 + ((sc ^ (t & 7)) * 8)) =
        *(const uint4*)(src + (size_t)(tt * 64 + t) * 3072 + sc * 8);
  }
  __syncthreads();
  const int d = tid >> 2, tq = tid & 3;
  bf16_t* dst = vT + ((size_t)((b * 16 + h) * 64 + d)) * TDIM + tt * 64;
#pragma unroll
  for (int p = 0; p < 2; ++p) {
    union { uint4 u; bf16_t e[8]; } o;
#pragma unroll
    for (int j = 0; j < 8; ++j) {
      const int t = p * 32 + tq * 8 + j;
      o.e[j] = tile[t * 64 + (((d >> 3) ^ (t & 7)) * 8) + (d & 7)];
    }
    *(uint4*)(dst + p * 32 + tq * 8) = o.u;
  }
}

// ---------------- fused LayerNorm (fp32 in) -> bf16 out -------------------------
__global__ __launch_bounds__(256)
void ln_kernel(const float* __restrict__ x, const float* __restrict__ g,
               const float* __restrict__ bta, bf16_t* __restrict__ out) {
  const size_t row = blockIdx.x;
  const int tid = threadIdx.x;
  const float4 v = ((const float4*)(x + row * CDIM))[tid];
  float s = v.x + v.y + v.z + v.w;
#pragma unroll
  for (int off = 1; off < 64; off <<= 1) s += __shfl_xor(s, off);
  __shared__ float r1[4], r2[4];
  const int wv = tid >> 6, lane = tid & 63;
  if (!lane) r1[wv] = s;
  __syncthreads();
  const float mu = (r1[0] + r1[1] + r1[2] + r1[3]) * (1.f / CDIM);
  const float dx = v.x - mu, dy = v.y - mu, dz = v.z - mu, dw = v.w - mu;
  float q = dx * dx + dy * dy + dz * dz + dw * dw;
#pragma unroll
  for (int off = 1; off < 64; off <<= 1) q += __shfl_xor(q, off);
  if (!lane) r2[wv] = q;
  __syncthreads();
  const float var = (r2[0] + r2[1] + r2[2] + r2[3]) * (1.f / CDIM);
  const float rs = rsqrtf(var + 1e-5f);
  const float4 gg = ((const float4*)g)[tid];
  const float4 bb = ((const float4*)bta)[tid];
  bf16x4 o;
  o[0] = (bf16_t)(dx * rs * gg.x + bb.x);
  o[1] = (bf16_t)(dy * rs * gg.y + bb.y);
  o[2] = (bf16_t)(dz * rs * gg.z + bb.z);
  o[3] = (bf16_t)(dw * rs * gg.w + bb.w);
  ((bf16x4*)(out + row * CDIM))[tid] = o;
}

enum { EPI_BF16 = 0, EPI_RESID = 1, EPI_GELU = 2 };

// ---------------- 256x256 8-wave counted-vmcnt MFMA GEMM ------------------------
template <int EPI>
__global__ __launch_bounds__(512)
void gemm256(const bf16_t* __restrict__ A, const bf16_t* __restrict__ Bt,
             const float* __restrict__ bias, const float* __restrict__ resid,
             void* __restrict__ outv, int M, int N, int K) {
  __shared__ bf16_t sA[2][256 * 64];
  __shared__ bf16_t sB[2][256 * 64];
  const int tid = threadIdx.x;
  const int lane = tid & 63, wv = tid >> 6;
  const int wm = wv >> 2, wn = wv & 3;
  const int rin = lane & 15, quad = lane >> 4;

  const int nwg = gridDim.x * gridDim.y;
  const int bid = blockIdx.y * gridDim.x + blockIdx.x;
  const int swzb = (bid & 7) * (nwg >> 3) + (bid >> 3);
  const int bx = swzb % gridDim.x, by = swzb / gridDim.x;
  const int m0 = by * 256, n0 = bx * 256;

  const int c8 = (lane & 7) ^ ((lane >> 3) & 7);
  const int aRow = wm * 128 + (wv & 3) * 8 + (lane >> 3);
  const int bRow = wn * 64 + (wv >> 2) * 8 + (lane >> 3);
  const bf16_t* srcA = A + (size_t)(m0 + aRow) * K + c8 * 8;
  const bf16_t* srcB = Bt + (size_t)(n0 + bRow) * K + c8 * 8;
  const int dstA = (wm * 128 + (wv & 3) * 8) * 64;
  const int dstB = (wn * 64 + (wv >> 2) * 8) * 64;

#define STA(buf, r, kk) gload16(srcA + (size_t)(32 * (r)) * K + (kk), (buf) + dstA + 32 * (r) * 64)
#define STB(buf, r, kk) gload16(srcB + (size_t)(16 * (r)) * K + (kk), (buf) + dstB + 16 * (r) * 64)

  const int ck0 = (quad ^ (rin & 7)) * 8;
  const int ck1 = ((4 + quad) ^ (rin & 7)) * 8;
  const int aBase = (wm * 128 + rin) * 64;
  const int bBase = (wn * 64 + rin) * 64;

  f32x4 acc[8][4] = {};
  bf16x8 af[8][2], bfr[4][2];

#define RDA(mi) { af[mi][0] = *(const bf16x8*)(rA + aBase + (mi)*1024 + ck0); \
                  af[mi][1] = *(const bf16x8*)(rA + aBase + (mi)*1024 + ck1); }
#define RDB(ni) { bfr[ni][0] = *(const bf16x8*)(rB + bBase + (ni)*1024 + ck0); \
                  bfr[ni][1] = *(const bf16x8*)(rB + bBase + (ni)*1024 + ck1); }
#define MM(mi, ni) { acc[mi][ni] = __builtin_amdgcn_mfma_f32_16x16x32_bf16(af[mi][0], bfr[ni][0], acc[mi][ni], 0, 0, 0); \
                     acc[mi][ni] = __builtin_amdgcn_mfma_f32_16x16x32_bf16(af[mi][1], bfr[ni][1], acc[mi][ni], 0, 0, 0); }

  const int NT = K >> 6;

  STA(sA[0], 0, 0); STB(sB[0], 0, 0); STB(sB[0], 1, 0);
  STA(sA[0], 1, 0); STB(sB[0], 2, 0); STB(sB[0], 3, 0);
  STA(sA[0], 2, 0);
  STA(sA[0], 3, 0);
  asm volatile("s_waitcnt vmcnt(5)" ::: "memory");
  S_BARRIER();

  for (int t = 0; t < NT; ++t) {
    const bf16_t* rA = sA[t & 1];
    const bf16_t* rB = sB[t & 1];
    bf16_t* wA = sA[(t & 1) ^ 1];
    bf16_t* wB = sB[(t & 1) ^ 1];
    const int kk = (t + 1 < NT ? t + 1 : t) * 64;

    RDA(0) RDA(1) RDB(0) RDB(1)
    asm volatile("s_waitcnt vmcnt(2)" ::: "memory");
    S_BARRIER();
    STA(wA, 0, kk); STB(wB, 0, kk); STB(wB, 1, kk);
    __builtin_amdgcn_s_setprio(1);
    MM(0, 0) MM(0, 1) MM(1, 0) MM(1, 1)
    __builtin_amdgcn_s_setprio(0);

    RDA(2) RDA(3) RDB(2) RDB(3)
    asm volatile("s_waitcnt vmcnt(4)" ::: "memory");
    S_BARRIER();
    STA(wA, 1, kk); STB(wB, 2, kk); STB(wB, 3, kk);
    __builtin_amdgcn_s_setprio(1);
    MM(0, 2) MM(0, 3) MM(1, 2) MM(1, 3) MM(2, 0) MM(2, 1) MM(3, 0) MM(3, 1)
    __builtin_amdgcn_s_setprio(0);

    RDA(4) RDA(5)
    asm volatile("s_waitcnt vmcnt(6)" ::: "memory");
    S_BARRIER();
    STA(wA, 2, kk);
    __builtin_amdgcn_s_setprio(1);
    MM(2, 2) MM(2, 3) MM(3, 2) MM(3, 3) MM(4, 0) MM(4, 1) MM(5, 0) MM(5, 1)
    __builtin_amdgcn_s_setprio(0);

    RDA(6) RDA(7)
    asm volatile("s_waitcnt vmcnt(4)" ::: "memory");
    S_BARRIER();
    STA(wA, 3, kk);
    __builtin_amdgcn_s_setprio(1);
    MM(4, 2) MM(4, 3) MM(5, 2) MM(5, 3) MM(6, 0) MM(6, 1) MM(7, 0) MM(7, 1)
    MM(6, 2) MM(6, 3) MM(7, 2) MM(7, 3)
    __builtin_amdgcn_s_setprio(0);
  }
  asm volatile("s_waitcnt vmcnt(0)" ::: "memory");

  const int rbase = m0 + wm * 128 + quad * 4;
  const int cbase = n0 + wn * 64 + rin;
#pragma unroll
  for (int mi = 0; mi < 8; ++mi)
#pragma unroll
    for (int ni = 0; ni < 4; ++ni)
#pragma unroll
      for (int r = 0; r < 4; ++r) {
        const int m = rbase + mi * 16 + r;
        const int n = cbase + ni * 16;
        float v = acc[mi][ni][r] + bias[n];
        if (EPI == EPI_RESID) v += resid[(size_t)m * N + n];
        if (EPI == EPI_GELU) v = 0.5f * v * (1.0f + erff(v * 0.7071067811865476f));
        if (EPI == EPI_RESID)
          ((float*)outv)[(size_t)m * N + n] = v;
        else
          ((bf16_t*)outv)[(size_t)m * N + n] = (bf16_t)v;
      }
#undef STA
#undef STB
#undef RDA
#undef RDB
#undef MM
}

// ---------------- 256x128 8-wave ring-3 MFMA GEMM (for N=1024 / qkv grids) ------
template <int EPI>
__global__ __launch_bounds__(512)
void gemm128(const bf16_t* __restrict__ A, const bf16_t* __restrict__ Bt,
             const float* __restrict__ bias, const float* __restrict__ resid,
             void* __restrict__ outv, int M, int N, int K) {
  __shared__ bf16_t sA[3][256 * 64];
  __shared__ bf16_t sB[3][128 * 64];
  const int tid = threadIdx.x;
  const int lane = tid & 63, wv = tid >> 6;
  const int wm = wv >> 1, wn = wv & 1;
  const int rin = lane & 15, quad = lane >> 4;

  const int nwg = gridDim.x * gridDim.y;
  const int bid = blockIdx.y * gridDim.x + blockIdx.x;
  const int swzb = (bid & 7) * (nwg >> 3) + (bid >> 3);
  const int bx = swzb % gridDim.x, by = swzb / gridDim.x;
  const int m0 = by * 256, n0 = bx * 128;

  const int c8 = (lane & 7) ^ ((lane >> 3) & 7);
  const bf16_t* srcA = A + (size_t)(m0 + 8 * wv + (lane >> 3)) * K + c8 * 8;
  const int dstA = (8 * wv) * 64;
  const bf16_t* srcB = Bt + (size_t)(n0 + (wv >> 2) * 64 + (wv & 3) * 8 + (lane >> 3)) * K + c8 * 8;
  const int dstB = ((wv >> 2) * 64 + (wv & 3) * 8) * 64;

#define STA(buf, r, kk) gload16(srcA + (size_t)(64 * (r)) * K + (kk), (buf) + dstA + 64 * (r) * 64)
#define STB(buf, r, kk) gload16(srcB + (size_t)(32 * (r)) * K + (kk), (buf) + dstB + 32 * (r) * 64)

  const int ck0 = (quad ^ (rin & 7)) * 8;
  const int ck1 = ((4 + quad) ^ (rin & 7)) * 8;
  const int aBase = (wm * 64 + rin) * 64;
  const int bBase = (wn * 64 + rin) * 64;

  f32x4 acc[4][4] = {};
  bf16x8 af[4][2], bfr[4][2];

#define RDA(mi) { af[mi][0] = *(const bf16x8*)(rA + aBase + (mi)*1024 + ck0); \
                  af[mi][1] = *(const bf16x8*)(rA + aBase + (mi)*1024 + ck1); }
#define RDB(ni) { bfr[ni][0] = *(const bf16x8*)(rB + bBase + (ni)*1024 + ck0); \
                  bfr[ni][1] = *(const bf16x8*)(rB + bBase + (ni)*1024 + ck1); }
#define MM(mi, ni) { acc[mi][ni] = __builtin_amdgcn_mfma_f32_16x16x32_bf16(af[mi][0], bfr[ni][0], acc[mi][ni], 0, 0, 0); \
                     acc[mi][ni] = __builtin_amdgcn_mfma_f32_16x16x32_bf16(af[mi][1], bfr[ni][1], acc[mi][ni], 0, 0, 0); }

  const int NT = K >> 6;

  STA(sA[0], 0, 0); STA(sA[0], 1, 0); STA(sA[0], 2, 0); STA(sA[0], 3, 0); STB(sB[0], 0, 0);
  STB(sB[0], 1, 0);
  STA(sA[1], 0, 64); STA(sA[1], 1, 64); STA(sA[1], 2, 64); STA(sA[1], 3, 64); STB(sB[1], 0, 64);
  STB(sB[1], 1, 64);
  asm volatile("s_waitcnt vmcnt(7)" ::: "memory");
  S_BARRIER();

  int rb = 0, wb = 2;
  for (int t = 0; t < NT; ++t) {
    const bf16_t* rA = sA[rb];
    const bf16_t* rB = sB[rb];
    bf16_t* wA = sA[wb];
    bf16_t* wB = sB[wb];
    const int kk = (t + 2 < NT ? t + 2 : NT - 1) * 64;

    RDA(0) RDA(1) RDA(2) RDA(3) RDB(0) RDB(1)
    asm volatile("s_waitcnt vmcnt(6)" ::: "memory");
    S_BARRIER();
    STA(wA, 0, kk); STA(wA, 1, kk); STA(wA, 2, kk); STA(wA, 3, kk); STB(wB, 0, kk);
    __builtin_amdgcn_s_setprio(1);
    MM(0, 0) MM(0, 1) MM(1, 0) MM(1, 1) MM(2, 0) MM(2, 1) MM(3, 0) MM(3, 1)
    __builtin_amdgcn_s_setprio(0);

    RDB(2) RDB(3)
    asm volatile("s_waitcnt vmcnt(6)" ::: "memory");
    S_BARRIER();
    STB(wB, 1, kk);
    __builtin_amdgcn_s_setprio(1);
    MM(0, 2) MM(0, 3) MM(1, 2) MM(1, 3) MM(2, 2) MM(2, 3) MM(3, 2) MM(3, 3)
    __builtin_amdgcn_s_setprio(0);

    rb = (rb == 2) ? 0 : rb + 1;
    wb = (wb == 2) ? 0 : wb + 1;
  }
  asm volatile("s_waitcnt vmcnt(0)" ::: "memory");

  const int rbase = m0 + wm * 64 + quad * 4;
  const int cbase = n0 + wn * 64 + rin;
#pragma unroll
  for (int mi = 0; mi < 4; ++mi)
#pragma unroll
    for (int ni = 0; ni < 4; ++ni)
#pragma unroll
      for (int r = 0; r < 4; ++r) {
        const int m = rbase + mi * 16 + r;
        const int n = cbase + ni * 16;
        float v = acc[mi][ni][r] + bias[n];
        if (EPI == EPI_RESID) v += resid[(size_t)m * N + n];
        if (EPI == EPI_GELU) v = 0.5f * v * (1.0f + erff(v * 0.7071067811865476f));
        if (EPI == EPI_RESID)
          ((float*)outv)[(size_t)m * N + n] = v;
        else
          ((bf16_t*)outv)[(size_t)m * N + n] = (bf16_t)v;
      }
#undef STA
#undef STB
#undef RDA
#undef RDB
#undef MM
}

// ---------------- flash attention v4.1, causal, H=16 D=64 ----------------------
// 64-row q-tiles, pair (i, 31-i) -> 1024 uniform blocks (33 k-tiles each) of 256
// threads (4 waves x 16 q-rows). K [t][d] and pre-transposed V^T [d][t] staged
// via async gload16 (pre-swizzled global source, chunk ^= row&7; linear LDS
// dest) -> zero ds_writes, conflict-free swizzled ds_reads.
// DEPTH-1 double buffer (v4 raced: prefetching kt+2 lands in the buffer being
// read THIS iteration). At iter kt: stage kt+1 into buf^1 (held tile kt-1,
// whose reads completed before the end-of-iter-(kt-1) barrier all waves have
// passed); compute from buf kt&1; vmcnt(0)+barrier (tile kt+1 must be
// resident next iter; the drain is hidden by 4 blocks/CU of TLP).
// 1D grid, id = bx*64 + (h + 16*b): all 16 blocks sharing one (b,h) K/V land
// on the same XCD under round-robin dispatch -> K/V fetched once per L2.
__global__ __launch_bounds__(256)
void attn_kernel(const bf16_t* __restrict__ qkv, const bf16_t* __restrict__ vT,
                 bf16_t* __restrict__ y) {
  const int id = blockIdx.x;
  const int bx = id >> 6;
  const int h = id & 15, b = (id >> 4) & 3;
  const int tid = threadIdx.x, lane = tid & 63, wv = tid >> 6;
  const int rin = lane & 15, quad = lane >> 4;

  __shared__ bf16_t K2[2][64 * 64];  // K [t][d], chunk ^ (t&7)
  __shared__ bf16_t V2[2][64 * 64];  // V^T [d][t], chunk ^ (d&7)

  const size_t base3 = (size_t)(b * TDIM) * 3072;
  const bf16_t* Kg = qkv + base3 + 1024 + h * 64;                 // + t*3072
  const bf16_t* Vg = vT + (size_t)((b * 16 + h) * 64) * TDIM;     // + d*2048
  const int sr = tid >> 3, sc = tid & 7;  // staging: row sr(+32), chunk sc
  const int sx = (sc ^ (sr & 7)) * 8;     // pre-swizzled source chunk
  const short4v ones = {(short)0x3F80, (short)0x3F80, (short)0x3F80, (short)0x3F80};

#define STAGE(bi, kt_) { \
    gload16(Kg + (size_t)((kt_) * 64 + sr) * 3072 + sx,      K2[bi] + sr * 64 + sc * 8);        \
    gload16(Kg + (size_t)((kt_) * 64 + 32 + sr) * 3072 + sx, K2[bi] + (32 + sr) * 64 + sc * 8); \
    gload16(Vg + (size_t)sr * TDIM + (kt_) * 64 + sx,        V2[bi] + sr * 64 + sc * 8);        \
    gload16(Vg + (size_t)(32 + sr) * TDIM + (kt_) * 64 + sx, V2[bi] + (32 + sr) * 64 + sc * 8); }

#pragma unroll 1
  for (int seg = 0; seg < 2; ++seg) {
    const int qt = seg ? bx : (31 - bx);  // long tile first
    const int q0 = qt * 64;
    const int nkt = qt + 1;

    // Q fragments (B-operand of S^T: col=q=rin, k=d)
    bf16x8 aq[2];
    {
      const size_t qr = base3 + (size_t)(q0 + wv * 16 + rin) * 3072 + h * 64;
      aq[0] = *(const bf16x8*)(qkv + qr + quad * 8);
      aq[1] = *(const bf16x8*)(qkv + qr + 32 + quad * 8);
    }

    f32x4 o[4] = {};
    f32x4 ol = {};

    STAGE(0, 0)
    asm volatile("s_waitcnt vmcnt(0)" ::: "memory");  // tile0 landed
    S_BARRIER();

    for (int kt = 0; kt < nkt; ++kt) {
      const bf16_t* Kb = K2[kt & 1];
      const bf16_t* Vb = V2[kt & 1];
      // depth-1 prefetch into buf^1 (tile kt-1's reads all retired pre-barrier)
      if (kt + 1 < nkt) STAGE((kt + 1) & 1, kt + 1)
      // ---- S^T = K.Q^T : 8 MFMA (M=key, N=q)
      f32x4 st[4] = {};
#pragma unroll
      for (int ki = 0; ki < 2; ++ki) {
#pragma unroll
        for (int kf = 0; kf < 4; ++kf) {
          const bf16x8 ak = *(const bf16x8*)(Kb + (kf * 16 + rin) * 64 +
                                             (((ki * 4 + quad) ^ (rin & 7)) * 8));
          st[kf] = __builtin_amdgcn_mfma_f32_16x16x32_bf16(ak, aq[ki], st[kf], 0, 0, 0);
        }
      }
      // ---- softmax (no max-sub) + pack into PV A-frags (k = quad*4+r)
      const bool maskt = (kt == qt);
      const int qg = q0 + wv * 16 + rin;
      short4v pf[4];
#pragma unroll
      for (int kf = 0; kf < 4; ++kf)
#pragma unroll
        for (int r = 0; r < 4; ++r) {
          const int kg = kt * 64 + kf * 16 + quad * 4 + r;
          float p = __builtin_amdgcn_exp2f(st[kf][r] * 0.18033688f);
          if (maskt && kg > qg) p = 0.f;
          union { bf16_t bv; short sv; } cv;
          cv.bv = (bf16_t)p;
          pf[kf][r] = cv.sv;
        }
      // ---- PV + rowsum: 20 MFMA 16x16x16, B-frags b64 from V^T
#pragma unroll
      for (int kf = 0; kf < 4; ++kf) {
#pragma unroll
        for (int nd = 0; nd < 4; ++nd) {
          const short4v bv = *(const short4v*)(Vb + (nd * 16 + rin) * 64 +
                                               (((kf * 2 + (quad >> 1)) ^ (rin & 7)) * 8) +
                                               (quad & 1) * 4);
          o[nd] = __builtin_amdgcn_mfma_f32_16x16x16bf16_1k(pf[kf], bv, o[nd], 0, 0, 0);
        }
        ol = __builtin_amdgcn_mfma_f32_16x16x16bf16_1k(pf[kf], ones, ol, 0, 0, 0);
      }
      asm volatile("s_waitcnt vmcnt(0)" ::: "memory");  // next tile resident
      S_BARRIER();
    }

    // ---- epilogue: O C-frag col=d=rin, row=q=quad*4+r; l frag reg=q
#pragma unroll
    for (int r = 0; r < 4; ++r) {
      const float inv = 1.0f / ol[r];
      const size_t row = (size_t)b * TDIM + q0 + wv * 16 + quad * 4 + r;
#pragma unroll
      for (int nd = 0; nd < 4; ++nd)
        y[row * CDIM + h * 64 + nd * 16 + rin] = (bf16_t)(o[nd][r] * inv);
    }
  }
#undef STAGE
}

extern "C" void kernel_launch(void* const* d_in, const int* in_sizes, int n_in,
                              void* d_out, int out_size, void* d_ws, size_t ws_size,
                              hipStream_t stream) {
  const float* x      = (const float*)d_in[0];
  const float* w_attn = (const float*)d_in[1];
  const float* b_attn = (const float*)d_in[2];
  const float* w_proj = (const float*)d_in[3];
  const float* b_proj = (const float*)d_in[4];
  const float* ln1g   = (const float*)d_in[5];
  const float* ln1b   = (const float*)d_in[6];
  const float* ln2g   = (const float*)d_in[7];
  const float* ln2b   = (const float*)d_in[8];
  const float* w_fc   = (const float*)d_in[9];
  const float* b_fc   = (const float*)d_in[10];
  const float* w_fc2  = (const float*)d_in[11];
  const float* b_fc2  = (const float*)d_in[12];
  float* out = (float*)d_out;

  char* ws = (char*)d_ws;
  bf16_t* wTattn = (bf16_t*)(ws + 0);                    //  6291456 B (3072x1024)
  bf16_t* wTproj = (bf16_t*)(ws + 6291456);              //  2097152 B (1024x1024)
  bf16_t* wTfc   = (bf16_t*)(ws + 8388608);              //  8388608 B (4096x1024)
  bf16_t* wTfc2  = (bf16_t*)(ws + 16777216);             //  8388608 B (1024x4096)
  bf16_t* xn     = (bf16_t*)(ws + 25165824);             // 16777216 B (8192x1024); dead after qkv GEMM -> reused as vT
  float*  x2     = (float*)(ws + 41943040);              // 33554432 B (8192x1024)
  bf16_t* qkv    = (bf16_t*)(ws + 75497472);             // 50331648 B (8192x3072)
  bf16_t* yb     = (bf16_t*)(ws + 75497472 + 50331648);  // 16777216 B (8192x1024)
  bf16_t* hb     = (bf16_t*)(ws + 75497472);             // 67108864 B (8192x4096), reuses qkv+y
  bf16_t* vT     = xn;                                   // 16777216 B (4x16x64x2048), overlays xn

  // weights -> bf16 transposed
  transpose_cast<<<dim3(96, 32), 256, 0, stream>>>(w_attn, wTattn, 1024, 3072);
  transpose_cast<<<dim3(32, 32), 256, 0, stream>>>(w_proj, wTproj, 1024, 1024);
  transpose_cast<<<dim3(128, 32), 256, 0, stream>>>(w_fc, wTfc, 1024, 4096);
  transpose_cast<<<dim3(32, 128), 256, 0, stream>>>(w_fc2, wTfc2, 4096, 1024);

  // LN1 -> xn
  ln_kernel<<<8192, 256, 0, stream>>>(x, ln1g, ln1b, xn);
  // qkv = xn @ w_attn + b_attn   (bf16 out)
  gemm128<EPI_BF16><<<dim3(24, 32), 512, 0, stream>>>(xn, wTattn, b_attn, nullptr, qkv, 8192, 3072, 1024);
  // V -> V^T  (xn is dead now; vT overlays it)
  transpose_v<<<dim3(32, 16, 4), 256, 0, stream>>>(qkv, vT);
  // attention -> yb
  attn_kernel<<<dim3(1024), 256, 0, stream>>>(qkv, vT, yb);
  // x2 = x + yb @ w_proj + b_proj (fp32)
  gemm128<EPI_RESID><<<dim3(8, 32), 512, 0, stream>>>(yb, wTproj, b_proj, x, x2, 8192, 1024, 1024);
  // LN2 -> xn
  ln_kernel<<<8192, 256, 0, stream>>>(x2, ln2g, ln2b, xn);
  // hb = gelu(xn @ w_fc + b_fc)  (bf16)
  gemm256<EPI_GELU><<<dim3(16, 32), 512, 0, stream>>>(xn, wTfc, b_fc, nullptr, hb, 8192, 4096, 1024);
  // out = x2 + hb @ w_fc2 + b_fc2 (fp32)
  gemm128<EPI_RESID><<<dim3(8, 32), 512, 0, stream>>>(hb, wTfc2, b_fc2, x2, out, 8192, 1024, 4096);
}